// Round 2
// baseline (261.897 us; speedup 1.0000x reference)
//
#include <hip/hip_runtime.h>

#define N_NODES 100000
#define N_EDGES 1600000
#define DIM 128
#define LEAKY 0.01f
#define RS_STRIDE 132
#define WS_STRIDE 132
#define LSTRIDE 132      // fused-kernel LDS row stride (floats)
#define NBUCKET 391      // ceil(100000/256) nodes-per-bucket buckets (d>>8)
#define SB_EDGES 4096    // edges per sort_local block
#define NSB 391          // ceil(1600000/4096)

typedef short bf16x8 __attribute__((ext_vector_type(8)));
typedef float f32x4 __attribute__((ext_vector_type(4)));

static __device__ __forceinline__ unsigned short f2bf(float f) {
  unsigned int u = __float_as_uint(f);
  u = (u + 0x7fffu + ((u >> 16) & 1u)) >> 16;  // RNE
  return (unsigned short)u;
}

// ---------------------------------------------------------------------------
// K1: local bucket sort. Each block takes 4096 edges, histograms bucket
// (= dst>>8, 391 buckets), scans in LDS, stages sorted-by-bucket records in
// LDS, writes them out fully coalesced. Record: {src | localD<<17, attr}.
// Also emits counts[b][sb] (ushort) and srcOff[b][sb] (run start in binned).
// ---------------------------------------------------------------------------
__global__ __launch_bounds__(512) void sort_local_kernel(
    const int* __restrict__ ei, const float* __restrict__ attr,
    int2* __restrict__ binned, unsigned short* __restrict__ counts,
    int* __restrict__ srcOff) {
  __shared__ int hist[NBUCKET];
  __shared__ int cursor[NBUCKET];
  __shared__ int scanBuf[512];
  __shared__ int2 stage[SB_EDGES];  // 32 KB

  const int t = threadIdx.x;
  const int blk = blockIdx.x;
  const int base = blk * SB_EDGES;
  const int n = min(SB_EDGES, N_EDGES - base);

  if (t < NBUCKET) hist[t] = 0;
  __syncthreads();

  int myP[8];   // packed src|localD<<17, or -1 sentinel bucket
  int myB[8];
  float myA[8];
#pragma unroll
  for (int k = 0; k < 8; ++k) {
    int i = t + k * 512;
    if (i < n) {
      int e = base + i;
      int s = ei[e];
      int d = ei[N_EDGES + e];
      myA[k] = attr[e];
      myB[k] = d >> 8;
      myP[k] = s | ((d & 255) << 17);
      atomicAdd(&hist[myB[k]], 1);
    } else {
      myB[k] = -1;
    }
  }
  __syncthreads();

  // exclusive scan of hist (Hillis-Steele over 512)
  int v = (t < NBUCKET) ? hist[t] : 0;
  scanBuf[t] = v;
  __syncthreads();
  for (int off = 1; off < 512; off <<= 1) {
    int u = (t >= off) ? scanBuf[t - off] : 0;
    __syncthreads();
    scanBuf[t] += u;
    __syncthreads();
  }
  if (t < NBUCKET) {
    int excl = scanBuf[t] - v;
    cursor[t] = excl;
    counts[(size_t)t * NSB + blk] = (unsigned short)v;
    srcOff[(size_t)t * NSB + blk] = base + excl;
  }
  __syncthreads();

#pragma unroll
  for (int k = 0; k < 8; ++k) {
    if (myB[k] >= 0) {
      int loc = atomicAdd(&cursor[myB[k]], 1);
      stage[loc] = make_int2(myP[k], __float_as_int(myA[k]));
    }
  }
  __syncthreads();

  for (int i = t; i < n; i += 512) binned[base + i] = stage[i];
}

// ---------------------------------------------------------------------------
// K2a: bucketCount[b] = sum_sb counts[b][sb]
// ---------------------------------------------------------------------------
__global__ __launch_bounds__(128) void bucket_count_kernel(
    const unsigned short* __restrict__ counts, int* __restrict__ bucketCount) {
  __shared__ int red[128];
  const int b = blockIdx.x;
  const int t = threadIdx.x;
  int s = 0;
  for (int sb = t; sb < NSB; sb += 128) s += counts[(size_t)b * NSB + sb];
  red[t] = s;
  __syncthreads();
  for (int off = 64; off > 0; off >>= 1) {
    if (t < off) red[t] += red[t + off];
    __syncthreads();
  }
  if (t == 0) bucketCount[b] = red[0];
}

// ---------------------------------------------------------------------------
// K2b: exclusive scan of 391 bucket counts -> bucketBase
// ---------------------------------------------------------------------------
__global__ __launch_bounds__(512) void bucket_scan_kernel(
    const int* __restrict__ bucketCount, int* __restrict__ bucketBase) {
  __shared__ int s[512];
  const int t = threadIdx.x;
  int v = (t < NBUCKET) ? bucketCount[t] : 0;
  s[t] = v;
  __syncthreads();
  for (int off = 1; off < 512; off <<= 1) {
    int u = (t >= off) ? s[t - off] : 0;
    __syncthreads();
    s[t] += u;
    __syncthreads();
  }
  if (t < NBUCKET) bucketBase[t] = s[t] - v;
}

// ---------------------------------------------------------------------------
// K3: per-bucket counting sort -> csr + row_ptr. One block per bucket
// (256 nodes). One THREAD PER RUN (391 runs, avg len ~10.5) instead of the
// old per-record binary search: pass 1 histograms, pass 2 places. All csr
// writes for a bucket come from ONE block.
// ---------------------------------------------------------------------------
__global__ __launch_bounds__(448) void passB_kernel(
    const int2* __restrict__ binned, const unsigned short* __restrict__ counts,
    const int* __restrict__ srcOff, const int* __restrict__ bucketBase,
    int2* __restrict__ csr, int* __restrict__ row_ptr) {
  __shared__ int runSrc[NSB];
  __shared__ int runLen[NSB];
  __shared__ int hist[256];
  __shared__ int cur[256];
  __shared__ int scanBuf[256];

  const int b = blockIdx.x;
  const int t = threadIdx.x;

  if (t < NSB) {
    runSrc[t] = srcOff[(size_t)b * NSB + t];
    runLen[t] = (int)counts[(size_t)b * NSB + t];
  }
  if (t < 256) hist[t] = 0;
  __syncthreads();

  // pass 1: per-node histogram, one thread walks one run
  if (t < NSB) {
    const int src = runSrc[t];
    const int len = runLen[t];
    for (int j = 0; j < len; ++j) {
      int px = binned[src + j].x;
      atomicAdd(&hist[(px >> 17) & 255], 1);
    }
  }
  __syncthreads();

  // exclusive scan of 256 node counts
  int hv = (t < 256) ? hist[t] : 0;
  if (t < 256) scanBuf[t] = hv;
  __syncthreads();
  for (int off = 1; off < 256; off <<= 1) {
    int u = 0;
    if (t < 256 && t >= off) u = scanBuf[t - off];
    __syncthreads();
    if (t < 256) scanBuf[t] += u;
    __syncthreads();
  }
  const int bb = bucketBase[b];
  if (t < 256) {
    int excl = scanBuf[t] - hv;
    cur[t] = excl;
    int node = b * 256 + t;
    if (node < N_NODES) row_ptr[node] = bb + excl;
  }
  if (b == 0 && t == 0) row_ptr[N_NODES] = N_EDGES;
  __syncthreads();

  // pass 2: place records, one thread walks one run
  if (t < NSB) {
    const int src = runSrc[t];
    const int len = runLen[t];
    for (int j = 0; j < len; ++j) {
      int2 rec = binned[src + j];
      int ld = (rec.x >> 17) & 255;
      int pos = bb + atomicAdd(&cur[ld], 1);
      csr[pos] = make_int2(rec.x & 0x1FFFF, rec.y);
    }
  }
}

// ---------------------------------------------------------------------------
// x -> bf16 conversion (one float4 -> one ushort4 per thread)
// ---------------------------------------------------------------------------
__global__ __launch_bounds__(256) void x2b_kernel(
    const float4* __restrict__ x, ushort4* __restrict__ xb) {
  const int i = blockIdx.x * 256 + threadIdx.x;  // 3.2M exactly
  float4 v = x[i];
  ushort4 o;
  o.x = f2bf(v.x); o.y = f2bf(v.y); o.z = f2bf(v.z); o.w = f2bf(v.w);
  xb[i] = o;
}

// ---------------------------------------------------------------------------
// FUSED gather + linear: block = 256 threads / 16 nodes.
// Phase 1: each wave gathers 4 nodes (bf16 x, 2 feats/lane) -> LDS tile.
// Phase 2: MFMA 16x128 @ W^T (identical fragment layout to old linear_mfma),
// LeakyReLU, write out. Saves the 102 MB agg round-trip + one dispatch.
// ---------------------------------------------------------------------------
__global__ __launch_bounds__(256) void gather_linear_kernel(
    const unsigned short* __restrict__ xb, const int* __restrict__ row_ptr,
    const int2* __restrict__ csr, const bf16x8* __restrict__ wfrag,
    const float* __restrict__ bias, float* __restrict__ out) {
  __shared__ float Ls[16 * LSTRIDE];  // 8448 B

  const int w = threadIdx.x >> 6;
  const int lane = threadIdx.x & 63;
  const int nodeBase = blockIdx.x * 16;

  // ---- phase 1: gather 4 nodes per wave ----
#pragma unroll
  for (int k = 0; k < 4; ++k) {
    const int loc = w * 4 + k;
    const int node = nodeBase + loc;
    const int beg = row_ptr[node];
    const int end = row_ptr[node + 1];

    float2 acc = make_float2(0.f, 0.f);
    int e = beg;
    for (; e + 3 < end; e += 4) {
      int2 e0 = csr[e];
      int2 e1 = csr[e + 1];
      int2 e2 = csr[e + 2];
      int2 e3 = csr[e + 3];
      unsigned int u0 = *(const unsigned int*)(xb + (size_t)e0.x * DIM + lane * 2);
      unsigned int u1 = *(const unsigned int*)(xb + (size_t)e1.x * DIM + lane * 2);
      unsigned int u2 = *(const unsigned int*)(xb + (size_t)e2.x * DIM + lane * 2);
      unsigned int u3 = *(const unsigned int*)(xb + (size_t)e3.x * DIM + lane * 2);
      float a0 = __int_as_float(e0.y), a1 = __int_as_float(e1.y);
      float a2 = __int_as_float(e2.y), a3 = __int_as_float(e3.y);
      acc.x += __uint_as_float(u0 << 16) * a0;
      acc.y += __uint_as_float(u0 & 0xffff0000u) * a0;
      acc.x += __uint_as_float(u1 << 16) * a1;
      acc.y += __uint_as_float(u1 & 0xffff0000u) * a1;
      acc.x += __uint_as_float(u2 << 16) * a2;
      acc.y += __uint_as_float(u2 & 0xffff0000u) * a2;
      acc.x += __uint_as_float(u3 << 16) * a3;
      acc.y += __uint_as_float(u3 & 0xffff0000u) * a3;
    }
    for (; e < end; ++e) {
      int2 e0 = csr[e];
      float a0 = __int_as_float(e0.y);
      unsigned int u0 = *(const unsigned int*)(xb + (size_t)e0.x * DIM + lane * 2);
      acc.x += __uint_as_float(u0 << 16) * a0;
      acc.y += __uint_as_float(u0 & 0xffff0000u) * a0;
    }
    *(float2*)(Ls + loc * LSTRIDE + lane * 2) = acc;
  }
  __syncthreads();

  // ---- phase 2: 16x128 linear via MFMA ----
  const int m = lane & 15;
  const int quad = lane >> 4;

  bf16x8 afrag[4];
#pragma unroll
  for (int q = 0; q < 4; ++q) {
    const float* ap = Ls + m * LSTRIDE + q * 32 + quad * 8;
    const float4 f0 = *(const float4*)(ap);
    const float4 f1 = *(const float4*)(ap + 4);
    afrag[q][0] = (short)f2bf(f0.x); afrag[q][1] = (short)f2bf(f0.y);
    afrag[q][2] = (short)f2bf(f0.z); afrag[q][3] = (short)f2bf(f0.w);
    afrag[q][4] = (short)f2bf(f1.x); afrag[q][5] = (short)f2bf(f1.y);
    afrag[q][6] = (short)f2bf(f1.z); afrag[q][7] = (short)f2bf(f1.w);
  }

#pragma unroll
  for (int j = 0; j < 2; ++j) {
    const int nt = w * 2 + j;
    const float bv = bias[nt * 16 + m];
    f32x4 acc = {bv, bv, bv, bv};
#pragma unroll
    for (int q = 0; q < 4; ++q) {
      bf16x8 bfrag = wfrag[(nt * 4 + q) * 64 + lane];
      acc = __builtin_amdgcn_mfma_f32_16x16x32_bf16(afrag[q], bfrag, acc, 0, 0, 0);
    }
    const int col = nt * 16 + m;
#pragma unroll
    for (int i = 0; i < 4; ++i) {
      float v = acc[i];
      v = v >= 0.f ? v : v * LEAKY;
      out[(size_t)(nodeBase + quad * 4 + i) * DIM + col] = v;
    }
  }
}

// fp32-x gather (used when ws can't hold xb)
__global__ __launch_bounds__(256) void gather_f32_kernel(
    const float* __restrict__ x, const int* __restrict__ row_ptr,
    const int2* __restrict__ csr, float* __restrict__ out) {
  const int node = blockIdx.x * 4 + (threadIdx.x >> 6);
  const int lane = threadIdx.x & 63;

  const int beg = row_ptr[node];
  const int end = row_ptr[node + 1];

  float2 acc = make_float2(0.f, 0.f);
  int e = beg;
  for (; e + 3 < end; e += 4) {
    int2 e0 = csr[e];
    int2 e1 = csr[e + 1];
    int2 e2 = csr[e + 2];
    int2 e3 = csr[e + 3];
    float2 v0 = *(const float2*)(x + (size_t)e0.x * DIM + lane * 2);
    float2 v1 = *(const float2*)(x + (size_t)e1.x * DIM + lane * 2);
    float2 v2 = *(const float2*)(x + (size_t)e2.x * DIM + lane * 2);
    float2 v3 = *(const float2*)(x + (size_t)e3.x * DIM + lane * 2);
    float a0 = __int_as_float(e0.y), a1 = __int_as_float(e1.y);
    float a2 = __int_as_float(e2.y), a3 = __int_as_float(e3.y);
    acc.x += v0.x * a0; acc.y += v0.y * a0;
    acc.x += v1.x * a1; acc.y += v1.y * a1;
    acc.x += v2.x * a2; acc.y += v2.y * a2;
    acc.x += v3.x * a3; acc.y += v3.y * a3;
  }
  for (; e < end; ++e) {
    int2 e0 = csr[e];
    float a0 = __int_as_float(e0.y);
    float2 v0 = *(const float2*)(x + (size_t)e0.x * DIM + lane * 2);
    acc.x += v0.x * a0; acc.y += v0.y * a0;
  }
  *(float2*)(out + (size_t)node * DIM + lane * 2) = acc;
}

// ---------------------------------------------------------------------------
// W^T -> MFMA B-fragments (bf16, lane order), 8 blocks x 256.
// ---------------------------------------------------------------------------
__global__ __launch_bounds__(256) void w_frag_kernel(
    const float* __restrict__ W, bf16x8* __restrict__ wfrag) {
  const int gid = blockIdx.x * 256 + threadIdx.x;  // 0..2047
  const int lane = gid & 63;
  const int q = (gid >> 6) & 3;
  const int nt = gid >> 8;
  const int n = nt * 16 + (lane & 15);
  const int kb = q * 32 + ((lane >> 4) & 3) * 8;
  const float4 f0 = *(const float4*)(W + n * DIM + kb);
  const float4 f1 = *(const float4*)(W + n * DIM + kb + 4);
  bf16x8 frag;
  frag[0] = (short)f2bf(f0.x); frag[1] = (short)f2bf(f0.y);
  frag[2] = (short)f2bf(f0.z); frag[3] = (short)f2bf(f0.w);
  frag[4] = (short)f2bf(f1.x); frag[5] = (short)f2bf(f1.y);
  frag[6] = (short)f2bf(f1.z); frag[7] = (short)f2bf(f1.w);
  wfrag[gid] = frag;
}

// ---------------------------------------------------------------------------
// MFMA linear: out = LeakyReLU(agg @ W^T + b), in-place safe.
// (kept for the mid-size-ws fallback path)
// ---------------------------------------------------------------------------
__global__ __launch_bounds__(256) void linear_mfma_kernel(
    const float* __restrict__ agg, const bf16x8* __restrict__ wfrag,
    const float* __restrict__ bias, float* __restrict__ out) {
  const int wave = threadIdx.x >> 6;
  const int lane = threadIdx.x & 63;
  const int r0 = (blockIdx.x * 4 + wave) * 16;
  if (r0 >= N_NODES) return;

  const int m = lane & 15;
  const int quad = lane >> 4;
  const int row = r0 + m;

  bf16x8 afrag[4];
#pragma unroll
  for (int q = 0; q < 4; ++q) {
    const float* ap = agg + (size_t)row * DIM + q * 32 + quad * 8;
    const float4 f0 = *(const float4*)(ap);
    const float4 f1 = *(const float4*)(ap + 4);
    afrag[q][0] = (short)f2bf(f0.x); afrag[q][1] = (short)f2bf(f0.y);
    afrag[q][2] = (short)f2bf(f0.z); afrag[q][3] = (short)f2bf(f0.w);
    afrag[q][4] = (short)f2bf(f1.x); afrag[q][5] = (short)f2bf(f1.y);
    afrag[q][6] = (short)f2bf(f1.z); afrag[q][7] = (short)f2bf(f1.w);
  }

#pragma unroll
  for (int nt = 0; nt < 8; ++nt) {
    const float bv = bias[nt * 16 + m];
    f32x4 acc = {bv, bv, bv, bv};
#pragma unroll
    for (int q = 0; q < 4; ++q) {
      bf16x8 bfrag = wfrag[(nt * 4 + q) * 64 + lane];
      acc = __builtin_amdgcn_mfma_f32_16x16x32_bf16(afrag[q], bfrag, acc, 0, 0, 0);
    }
    const int col = nt * 16 + m;
#pragma unroll
    for (int i = 0; i < 4; ++i) {
      float v = acc[i];
      v = v >= 0.f ? v : v * LEAKY;
      out[(size_t)(r0 + quad * 4 + i) * DIM + col] = v;
    }
  }
}

// ---------------------------------------------------------------------------
// Fallback path (tiny ws): atomic scatter + LDS vector linear.
// ---------------------------------------------------------------------------
__global__ __launch_bounds__(256) void scatter_kernel(
    const float* __restrict__ x, const int* __restrict__ ei,
    const float* __restrict__ attr, float* __restrict__ agg) {
  int gid = blockIdx.x * blockDim.x + threadIdx.x;
  int e = gid >> 5;
  int f = (gid & 31) * 4;
  if (e >= N_EDGES) return;
  int s = ei[e];
  int d = ei[N_EDGES + e];
  float a = attr[e];
  const float4 xv = *(const float4*)(x + (size_t)s * DIM + f);
  float* dp = agg + (size_t)d * DIM + f;
  atomicAdd(dp + 0, xv.x * a);
  atomicAdd(dp + 1, xv.y * a);
  atomicAdd(dp + 2, xv.z * a);
  atomicAdd(dp + 3, xv.w * a);
}

__global__ __launch_bounds__(256, 2) void linear_kernel(
    const float* __restrict__ agg, const float* __restrict__ W,
    const float* __restrict__ bias, float* __restrict__ out) {
  __shared__ float Rs[32 * RS_STRIDE];
  __shared__ float Ws[64 * WS_STRIDE];

  const int tid = threadIdx.x;
  const int c = (tid & 31) * 4;
  const int rg = tid >> 5;
  const size_t rowBase = (size_t)blockIdx.x * 32;

  {
    const int lr = tid >> 3;
    const int col = (tid & 7) * 16;
    const float4* src = (const float4*)(agg + (rowBase + lr) * DIM + col);
#pragma unroll
    for (int j = 0; j < 4; ++j) {
      *(float4*)(Rs + lr * RS_STRIDE + col + j * 4) = src[j];
    }
  }

  const float4 bv = *(const float4*)(bias + c);
  float4 acc0 = bv, acc1 = bv, acc2 = bv, acc3 = bv;

  for (int half = 0; half < 2; ++half) {
    __syncthreads();
    {
      const int k0 = tid >> 7;
      const int o = tid & 127;
#pragma unroll
      for (int kk = k0; kk < 64; kk += 2) {
        Ws[kk * WS_STRIDE + o] = W[o * DIM + half * 64 + kk];
      }
    }
    __syncthreads();

    const float* rs0 = Rs + (rg * 4 + 0) * RS_STRIDE + half * 64;
    const float* rs1 = Rs + (rg * 4 + 1) * RS_STRIDE + half * 64;
    const float* rs2 = Rs + (rg * 4 + 2) * RS_STRIDE + half * 64;
    const float* rs3 = Rs + (rg * 4 + 3) * RS_STRIDE + half * 64;

#pragma unroll 8
    for (int k4 = 0; k4 < 16; ++k4) {
      const float4 v0 = *(const float4*)(rs0 + k4 * 4);
      const float4 v1 = *(const float4*)(rs1 + k4 * 4);
      const float4 v2 = *(const float4*)(rs2 + k4 * 4);
      const float4 v3 = *(const float4*)(rs3 + k4 * 4);
      const float4 w0 = *(const float4*)(Ws + (k4 * 4 + 0) * WS_STRIDE + c);
      const float4 w1 = *(const float4*)(Ws + (k4 * 4 + 1) * WS_STRIDE + c);
      const float4 w2 = *(const float4*)(Ws + (k4 * 4 + 2) * WS_STRIDE + c);
      const float4 w3 = *(const float4*)(Ws + (k4 * 4 + 3) * WS_STRIDE + c);

#define FMA4(acc, v)                                               \
      acc.x += v.x * w0.x + v.y * w1.x + v.z * w2.x + v.w * w3.x;  \
      acc.y += v.x * w0.y + v.y * w1.y + v.z * w2.y + v.w * w3.y;  \
      acc.z += v.x * w0.z + v.y * w1.z + v.z * w2.z + v.w * w3.z;  \
      acc.w += v.x * w0.w + v.y * w1.w + v.z * w2.w + v.w * w3.w;
      FMA4(acc0, v0)
      FMA4(acc1, v1)
      FMA4(acc2, v2)
      FMA4(acc3, v3)
#undef FMA4
    }
  }

#define LEAKY4(acc)                                   \
  acc.x = acc.x >= 0.f ? acc.x : acc.x * LEAKY;       \
  acc.y = acc.y >= 0.f ? acc.y : acc.y * LEAKY;       \
  acc.z = acc.z >= 0.f ? acc.z : acc.z * LEAKY;       \
  acc.w = acc.w >= 0.f ? acc.w : acc.w * LEAKY;
  LEAKY4(acc0) LEAKY4(acc1) LEAKY4(acc2) LEAKY4(acc3)
#undef LEAKY4

  const int row0 = (int)rowBase + rg * 4;
  *(float4*)(out + (size_t)(row0 + 0) * DIM + c) = acc0;
  *(float4*)(out + (size_t)(row0 + 1) * DIM + c) = acc1;
  *(float4*)(out + (size_t)(row0 + 2) * DIM + c) = acc2;
  *(float4*)(out + (size_t)(row0 + 3) * DIM + c) = acc3;
}

extern "C" void kernel_launch(void* const* d_in, const int* in_sizes, int n_in,
                              void* d_out, int out_size, void* d_ws, size_t ws_size,
                              hipStream_t stream) {
  const float* x = (const float*)d_in[0];
  const int* ei = (const int*)d_in[1];  // int32
  const float* attr = (const float*)d_in[2];
  const float* W = (const float*)d_in[3];
  const float* b = (const float*)d_in[4];
  float* out = (float*)d_out;

  // Workspace layout
  const size_t offBinned = 0;                             // E int2
  const size_t offCounts = 12812288;                      // 391*391 ushort
  const size_t offSrcOff = offCounts + 305920;            // 391*391 int
  const size_t offBCount = offSrcOff + 611584;            // 391 int
  const size_t offBBase  = offBCount + 1792;              // 391 int
  const size_t offCsr    = offBBase + 1792;               // E int2
  const size_t offRowPtr = offCsr + 12812288;             // N+1 int
  const size_t offWfrag  = offRowPtr + 400128;            // 32 KB
  const size_t sortNeed  = offWfrag + 32768;              // ~27.0 MB
  const size_t offXb     = sortNeed;                      // N*DIM bf16
  const size_t fullNeed  = offXb + 25600000;              // ~52.6 MB

  if (ws_size >= sortNeed) {
    char* ws = (char*)d_ws;
    int2* binned = (int2*)(ws + offBinned);
    unsigned short* counts = (unsigned short*)(ws + offCounts);
    int* srcOff = (int*)(ws + offSrcOff);
    int* bucketCount = (int*)(ws + offBCount);
    int* bucketBase = (int*)(ws + offBBase);
    int2* csr = (int2*)(ws + offCsr);
    int* row_ptr = (int*)(ws + offRowPtr);
    bf16x8* wfrag = (bf16x8*)(ws + offWfrag);

    w_frag_kernel<<<8, 256, 0, stream>>>(W, wfrag);
    sort_local_kernel<<<NSB, 512, 0, stream>>>(ei, attr, binned, counts, srcOff);
    bucket_count_kernel<<<NBUCKET, 128, 0, stream>>>(counts, bucketCount);
    bucket_scan_kernel<<<1, 512, 0, stream>>>(bucketCount, bucketBase);
    passB_kernel<<<NBUCKET, 448, 0, stream>>>(binned, counts, srcOff, bucketBase,
                                              csr, row_ptr);
    if (ws_size >= fullNeed) {
      unsigned short* xb = (unsigned short*)(ws + offXb);
      x2b_kernel<<<12500, 256, 0, stream>>>((const float4*)x, (ushort4*)xb);
      gather_linear_kernel<<<N_NODES / 16, 256, 0, stream>>>(xb, row_ptr, csr,
                                                             wfrag, b, out);
    } else {
      gather_f32_kernel<<<N_NODES / 4, 256, 0, stream>>>(x, row_ptr, csr, out);
      linear_mfma_kernel<<<(N_NODES + 63) / 64, 256, 0, stream>>>(out, wfrag, b, out);
    }
  } else {
    hipMemsetAsync(out, 0, (size_t)N_NODES * DIM * sizeof(float), stream);
    scatter_kernel<<<(N_EDGES * 32) / 256, 256, 0, stream>>>(x, ei, attr, out);
    linear_kernel<<<N_NODES / 32, 256, 0, stream>>>(out, W, b, out);
  }
}

// Round 3
// 249.471 us; speedup vs baseline: 1.0498x; 1.0498x over previous
//
#include <hip/hip_runtime.h>

#define N_NODES 100000
#define N_EDGES 1600000
#define DIM 128
#define LEAKY 0.01f
#define RS_STRIDE 132
#define WS_STRIDE 132
#define NBUCKET 391      // ceil(100000/256) nodes-per-bucket buckets (d>>8)
#define SB_EDGES 4096    // edges per sort_local block
#define NSB 391          // ceil(1600000/4096)

typedef short bf16x8 __attribute__((ext_vector_type(8)));
typedef float f32x4 __attribute__((ext_vector_type(4)));

static __device__ __forceinline__ unsigned short f2bf(float f) {
  unsigned int u = __float_as_uint(f);
  u = (u + 0x7fffu + ((u >> 16) & 1u)) >> 16;  // RNE
  return (unsigned short)u;
}

// ---------------------------------------------------------------------------
// K1: local bucket sort (+ fused x->bf16 conversion tail when xb != null).
// Each block takes 4096 edges, histograms bucket (= dst>>8, 391 buckets),
// scans in LDS, stages sorted-by-bucket records in LDS, writes them out
// fully coalesced. Record: {src | localD<<17, attr}. Also emits
// counts[b][sb] (ushort) and srcOff[b][sb] (run start in binned).
// ---------------------------------------------------------------------------
__global__ __launch_bounds__(512) void sort_local_kernel(
    const int* __restrict__ ei, const float* __restrict__ attr,
    int2* __restrict__ binned, unsigned short* __restrict__ counts,
    int* __restrict__ srcOff, const float4* __restrict__ x4,
    ushort4* __restrict__ xb4) {
  __shared__ int hist[NBUCKET];
  __shared__ int cursor[NBUCKET];
  __shared__ int scanBuf[512];
  __shared__ int2 stage[SB_EDGES];  // 32 KB

  const int t = threadIdx.x;
  const int blk = blockIdx.x;
  const int base = blk * SB_EDGES;
  const int n = min(SB_EDGES, N_EDGES - base);

  if (t < NBUCKET) hist[t] = 0;
  __syncthreads();

  int myP[8];   // packed src|localD<<17, or -1 sentinel bucket
  int myB[8];
  float myA[8];
#pragma unroll
  for (int k = 0; k < 8; ++k) {
    int i = t + k * 512;
    if (i < n) {
      int e = base + i;
      int s = ei[e];
      int d = ei[N_EDGES + e];
      myA[k] = attr[e];
      myB[k] = d >> 8;
      myP[k] = s | ((d & 255) << 17);
      atomicAdd(&hist[myB[k]], 1);
    } else {
      myB[k] = -1;
    }
  }
  __syncthreads();

  // exclusive scan of hist (Hillis-Steele over 512)
  int v = (t < NBUCKET) ? hist[t] : 0;
  scanBuf[t] = v;
  __syncthreads();
  for (int off = 1; off < 512; off <<= 1) {
    int u = (t >= off) ? scanBuf[t - off] : 0;
    __syncthreads();
    scanBuf[t] += u;
    __syncthreads();
  }
  if (t < NBUCKET) {
    int excl = scanBuf[t] - v;
    cursor[t] = excl;
    counts[(size_t)t * NSB + blk] = (unsigned short)v;
    srcOff[(size_t)t * NSB + blk] = base + excl;
  }
  __syncthreads();

#pragma unroll
  for (int k = 0; k < 8; ++k) {
    if (myB[k] >= 0) {
      int loc = atomicAdd(&cursor[myB[k]], 1);
      stage[loc] = make_int2(myP[k], __float_as_int(myA[k]));
    }
  }
  __syncthreads();

  for (int i = t; i < n; i += 512) binned[base + i] = stage[i];

  // fused x -> bf16 conversion (grid-stride over 3.2M float4)
  if (xb4) {
    for (int i = blk * 512 + t; i < (N_NODES * DIM) / 4; i += NSB * 512) {
      float4 vv = x4[i];
      ushort4 o;
      o.x = f2bf(vv.x); o.y = f2bf(vv.y); o.z = f2bf(vv.z); o.w = f2bf(vv.w);
      xb4[i] = o;
    }
  }
}

// ---------------------------------------------------------------------------
// K2a: bucketCount[b] = sum_sb counts[b][sb]
// ---------------------------------------------------------------------------
__global__ __launch_bounds__(128) void bucket_count_kernel(
    const unsigned short* __restrict__ counts, int* __restrict__ bucketCount) {
  __shared__ int red[128];
  const int b = blockIdx.x;
  const int t = threadIdx.x;
  int s = 0;
  for (int sb = t; sb < NSB; sb += 128) s += counts[(size_t)b * NSB + sb];
  red[t] = s;
  __syncthreads();
  for (int off = 64; off > 0; off >>= 1) {
    if (t < off) red[t] += red[t + off];
    __syncthreads();
  }
  if (t == 0) bucketCount[b] = red[0];
}

// ---------------------------------------------------------------------------
// K2b: exclusive scan of 391 bucket counts -> bucketBase
// ---------------------------------------------------------------------------
__global__ __launch_bounds__(512) void bucket_scan_kernel(
    const int* __restrict__ bucketCount, int* __restrict__ bucketBase) {
  __shared__ int s[512];
  const int t = threadIdx.x;
  int v = (t < NBUCKET) ? bucketCount[t] : 0;
  s[t] = v;
  __syncthreads();
  for (int off = 1; off < 512; off <<= 1) {
    int u = (t >= off) ? s[t - off] : 0;
    __syncthreads();
    s[t] += u;
    __syncthreads();
  }
  if (t < NBUCKET) bucketBase[t] = s[t] - v;
}

// ---------------------------------------------------------------------------
// K3: per-bucket counting sort -> csr + row_ptr. One block per bucket
// (256 nodes). One THREAD PER RUN (391 runs, avg len ~10.5): pass 1
// histograms, pass 2 places. All csr writes for a bucket from ONE block.
// ---------------------------------------------------------------------------
__global__ __launch_bounds__(448) void passB_kernel(
    const int2* __restrict__ binned, const unsigned short* __restrict__ counts,
    const int* __restrict__ srcOff, const int* __restrict__ bucketBase,
    int2* __restrict__ csr, int* __restrict__ row_ptr) {
  __shared__ int runSrc[NSB];
  __shared__ int runLen[NSB];
  __shared__ int hist[256];
  __shared__ int cur[256];
  __shared__ int scanBuf[256];

  const int b = blockIdx.x;
  const int t = threadIdx.x;

  if (t < NSB) {
    runSrc[t] = srcOff[(size_t)b * NSB + t];
    runLen[t] = (int)counts[(size_t)b * NSB + t];
  }
  if (t < 256) hist[t] = 0;
  __syncthreads();

  // pass 1: per-node histogram, one thread walks one run
  if (t < NSB) {
    const int src = runSrc[t];
    const int len = runLen[t];
    for (int j = 0; j < len; ++j) {
      int px = binned[src + j].x;
      atomicAdd(&hist[(px >> 17) & 255], 1);
    }
  }
  __syncthreads();

  // exclusive scan of 256 node counts
  int hv = (t < 256) ? hist[t] : 0;
  if (t < 256) scanBuf[t] = hv;
  __syncthreads();
  for (int off = 1; off < 256; off <<= 1) {
    int u = 0;
    if (t < 256 && t >= off) u = scanBuf[t - off];
    __syncthreads();
    if (t < 256) scanBuf[t] += u;
    __syncthreads();
  }
  const int bb = bucketBase[b];
  if (t < 256) {
    int excl = scanBuf[t] - hv;
    cur[t] = excl;
    int node = b * 256 + t;
    if (node < N_NODES) row_ptr[node] = bb + excl;
  }
  if (b == 0 && t == 0) row_ptr[N_NODES] = N_EDGES;
  __syncthreads();

  // pass 2: place records, one thread walks one run
  if (t < NSB) {
    const int src = runSrc[t];
    const int len = runLen[t];
    for (int j = 0; j < len; ++j) {
      int2 rec = binned[src + j];
      int ld = (rec.x >> 17) & 255;
      int pos = bb + atomicAdd(&cur[ld], 1);
      csr[pos] = make_int2(rec.x & 0x1FFFF, rec.y);
    }
  }
}

// ---------------------------------------------------------------------------
// Gather aggregation (bf16 x) -> packed-bf16 agg. One wave per node,
// 2 feats per lane. Identical structure to the verified 76 us gather;
// only the final store differs (u32 of 2xbf16 instead of float2).
// Numerically identical to f32-agg + f2bf-in-linear (same rounding point).
// ---------------------------------------------------------------------------
__global__ __launch_bounds__(256) void gather_aggb_kernel(
    const unsigned short* __restrict__ xb, const int* __restrict__ row_ptr,
    const int2* __restrict__ csr, unsigned int* __restrict__ aggB) {
  const int node = blockIdx.x * 4 + (threadIdx.x >> 6);
  const int lane = threadIdx.x & 63;

  const int beg = row_ptr[node];
  const int end = row_ptr[node + 1];

  float2 acc = make_float2(0.f, 0.f);
  int e = beg;
  for (; e + 3 < end; e += 4) {
    int2 e0 = csr[e];
    int2 e1 = csr[e + 1];
    int2 e2 = csr[e + 2];
    int2 e3 = csr[e + 3];
    unsigned int u0 = *(const unsigned int*)(xb + (size_t)e0.x * DIM + lane * 2);
    unsigned int u1 = *(const unsigned int*)(xb + (size_t)e1.x * DIM + lane * 2);
    unsigned int u2 = *(const unsigned int*)(xb + (size_t)e2.x * DIM + lane * 2);
    unsigned int u3 = *(const unsigned int*)(xb + (size_t)e3.x * DIM + lane * 2);
    float a0 = __int_as_float(e0.y), a1 = __int_as_float(e1.y);
    float a2 = __int_as_float(e2.y), a3 = __int_as_float(e3.y);
    acc.x += __uint_as_float(u0 << 16) * a0;
    acc.y += __uint_as_float(u0 & 0xffff0000u) * a0;
    acc.x += __uint_as_float(u1 << 16) * a1;
    acc.y += __uint_as_float(u1 & 0xffff0000u) * a1;
    acc.x += __uint_as_float(u2 << 16) * a2;
    acc.y += __uint_as_float(u2 & 0xffff0000u) * a2;
    acc.x += __uint_as_float(u3 << 16) * a3;
    acc.y += __uint_as_float(u3 & 0xffff0000u) * a3;
  }
  for (; e < end; ++e) {
    int2 e0 = csr[e];
    float a0 = __int_as_float(e0.y);
    unsigned int u0 = *(const unsigned int*)(xb + (size_t)e0.x * DIM + lane * 2);
    acc.x += __uint_as_float(u0 << 16) * a0;
    acc.y += __uint_as_float(u0 & 0xffff0000u) * a0;
  }
  aggB[(size_t)node * 64 + lane] =
      (unsigned int)f2bf(acc.x) | ((unsigned int)f2bf(acc.y) << 16);
}

// Verified r1 gather (f32 agg into out) — mid-ws fallback.
__global__ __launch_bounds__(256) void gather_bf16_kernel(
    const unsigned short* __restrict__ xb, const int* __restrict__ row_ptr,
    const int2* __restrict__ csr, float* __restrict__ out) {
  const int node = blockIdx.x * 4 + (threadIdx.x >> 6);
  const int lane = threadIdx.x & 63;

  const int beg = row_ptr[node];
  const int end = row_ptr[node + 1];

  float2 acc = make_float2(0.f, 0.f);
  int e = beg;
  for (; e + 3 < end; e += 4) {
    int2 e0 = csr[e];
    int2 e1 = csr[e + 1];
    int2 e2 = csr[e + 2];
    int2 e3 = csr[e + 3];
    unsigned int u0 = *(const unsigned int*)(xb + (size_t)e0.x * DIM + lane * 2);
    unsigned int u1 = *(const unsigned int*)(xb + (size_t)e1.x * DIM + lane * 2);
    unsigned int u2 = *(const unsigned int*)(xb + (size_t)e2.x * DIM + lane * 2);
    unsigned int u3 = *(const unsigned int*)(xb + (size_t)e3.x * DIM + lane * 2);
    float a0 = __int_as_float(e0.y), a1 = __int_as_float(e1.y);
    float a2 = __int_as_float(e2.y), a3 = __int_as_float(e3.y);
    acc.x += __uint_as_float(u0 << 16) * a0;
    acc.y += __uint_as_float(u0 & 0xffff0000u) * a0;
    acc.x += __uint_as_float(u1 << 16) * a1;
    acc.y += __uint_as_float(u1 & 0xffff0000u) * a1;
    acc.x += __uint_as_float(u2 << 16) * a2;
    acc.y += __uint_as_float(u2 & 0xffff0000u) * a2;
    acc.x += __uint_as_float(u3 << 16) * a3;
    acc.y += __uint_as_float(u3 & 0xffff0000u) * a3;
  }
  for (; e < end; ++e) {
    int2 e0 = csr[e];
    float a0 = __int_as_float(e0.y);
    unsigned int u0 = *(const unsigned int*)(xb + (size_t)e0.x * DIM + lane * 2);
    acc.x += __uint_as_float(u0 << 16) * a0;
    acc.y += __uint_as_float(u0 & 0xffff0000u) * a0;
  }
  *(float2*)(out + (size_t)node * DIM + lane * 2) = acc;
}

// fp32-x gather (used when ws can't hold xb)
__global__ __launch_bounds__(256) void gather_f32_kernel(
    const float* __restrict__ x, const int* __restrict__ row_ptr,
    const int2* __restrict__ csr, float* __restrict__ out) {
  const int node = blockIdx.x * 4 + (threadIdx.x >> 6);
  const int lane = threadIdx.x & 63;

  const int beg = row_ptr[node];
  const int end = row_ptr[node + 1];

  float2 acc = make_float2(0.f, 0.f);
  int e = beg;
  for (; e + 3 < end; e += 4) {
    int2 e0 = csr[e];
    int2 e1 = csr[e + 1];
    int2 e2 = csr[e + 2];
    int2 e3 = csr[e + 3];
    float2 v0 = *(const float2*)(x + (size_t)e0.x * DIM + lane * 2);
    float2 v1 = *(const float2*)(x + (size_t)e1.x * DIM + lane * 2);
    float2 v2 = *(const float2*)(x + (size_t)e2.x * DIM + lane * 2);
    float2 v3 = *(const float2*)(x + (size_t)e3.x * DIM + lane * 2);
    float a0 = __int_as_float(e0.y), a1 = __int_as_float(e1.y);
    float a2 = __int_as_float(e2.y), a3 = __int_as_float(e3.y);
    acc.x += v0.x * a0; acc.y += v0.y * a0;
    acc.x += v1.x * a1; acc.y += v1.y * a1;
    acc.x += v2.x * a2; acc.y += v2.y * a2;
    acc.x += v3.x * a3; acc.y += v3.y * a3;
  }
  for (; e < end; ++e) {
    int2 e0 = csr[e];
    float a0 = __int_as_float(e0.y);
    float2 v0 = *(const float2*)(x + (size_t)e0.x * DIM + lane * 2);
    acc.x += v0.x * a0; acc.y += v0.y * a0;
  }
  *(float2*)(out + (size_t)node * DIM + lane * 2) = acc;
}

// ---------------------------------------------------------------------------
// W^T -> MFMA B-fragments (bf16, lane order), 8 blocks x 256.
// ---------------------------------------------------------------------------
__global__ __launch_bounds__(256) void w_frag_kernel(
    const float* __restrict__ W, bf16x8* __restrict__ wfrag) {
  const int gid = blockIdx.x * 256 + threadIdx.x;  // 0..2047
  const int lane = gid & 63;
  const int q = (gid >> 6) & 3;
  const int nt = gid >> 8;
  const int n = nt * 16 + (lane & 15);
  const int kb = q * 32 + ((lane >> 4) & 3) * 8;
  const float4 f0 = *(const float4*)(W + n * DIM + kb);
  const float4 f1 = *(const float4*)(W + n * DIM + kb + 4);
  bf16x8 frag;
  frag[0] = (short)f2bf(f0.x); frag[1] = (short)f2bf(f0.y);
  frag[2] = (short)f2bf(f0.z); frag[3] = (short)f2bf(f0.w);
  frag[4] = (short)f2bf(f1.x); frag[5] = (short)f2bf(f1.y);
  frag[6] = (short)f2bf(f1.z); frag[7] = (short)f2bf(f1.w);
  wfrag[gid] = frag;
}

// ---------------------------------------------------------------------------
// MFMA linear from packed-bf16 agg: direct 16B fragment loads, no cvt VALU.
// out = LeakyReLU(aggB @ W^T + b).
// ---------------------------------------------------------------------------
__global__ __launch_bounds__(256) void linear_mfma_bf16_kernel(
    const unsigned short* __restrict__ aggB, const bf16x8* __restrict__ wfrag,
    const float* __restrict__ bias, float* __restrict__ out) {
  const int wave = threadIdx.x >> 6;
  const int lane = threadIdx.x & 63;
  const int r0 = (blockIdx.x * 4 + wave) * 16;
  if (r0 >= N_NODES) return;

  const int m = lane & 15;
  const int quad = lane >> 4;
  const int row = r0 + m;

  bf16x8 afrag[4];
#pragma unroll
  for (int q = 0; q < 4; ++q) {
    afrag[q] = *(const bf16x8*)(aggB + (size_t)row * DIM + q * 32 + quad * 8);
  }

#pragma unroll
  for (int nt = 0; nt < 8; ++nt) {
    const float bv = bias[nt * 16 + m];
    f32x4 acc = {bv, bv, bv, bv};
#pragma unroll
    for (int q = 0; q < 4; ++q) {
      bf16x8 bfrag = wfrag[(nt * 4 + q) * 64 + lane];
      acc = __builtin_amdgcn_mfma_f32_16x16x32_bf16(afrag[q], bfrag, acc, 0, 0, 0);
    }
    const int col = nt * 16 + m;
#pragma unroll
    for (int i = 0; i < 4; ++i) {
      float v = acc[i];
      v = v >= 0.f ? v : v * LEAKY;
      out[(size_t)(r0 + quad * 4 + i) * DIM + col] = v;
    }
  }
}

// ---------------------------------------------------------------------------
// MFMA linear from f32 agg (verified r1), in-place safe — mid-ws fallback.
// ---------------------------------------------------------------------------
__global__ __launch_bounds__(256) void linear_mfma_kernel(
    const float* __restrict__ agg, const bf16x8* __restrict__ wfrag,
    const float* __restrict__ bias, float* __restrict__ out) {
  const int wave = threadIdx.x >> 6;
  const int lane = threadIdx.x & 63;
  const int r0 = (blockIdx.x * 4 + wave) * 16;
  if (r0 >= N_NODES) return;

  const int m = lane & 15;
  const int quad = lane >> 4;
  const int row = r0 + m;

  bf16x8 afrag[4];
#pragma unroll
  for (int q = 0; q < 4; ++q) {
    const float* ap = agg + (size_t)row * DIM + q * 32 + quad * 8;
    const float4 f0 = *(const float4*)(ap);
    const float4 f1 = *(const float4*)(ap + 4);
    afrag[q][0] = (short)f2bf(f0.x); afrag[q][1] = (short)f2bf(f0.y);
    afrag[q][2] = (short)f2bf(f0.z); afrag[q][3] = (short)f2bf(f0.w);
    afrag[q][4] = (short)f2bf(f1.x); afrag[q][5] = (short)f2bf(f1.y);
    afrag[q][6] = (short)f2bf(f1.z); afrag[q][7] = (short)f2bf(f1.w);
  }

#pragma unroll
  for (int nt = 0; nt < 8; ++nt) {
    const float bv = bias[nt * 16 + m];
    f32x4 acc = {bv, bv, bv, bv};
#pragma unroll
    for (int q = 0; q < 4; ++q) {
      bf16x8 bfrag = wfrag[(nt * 4 + q) * 64 + lane];
      acc = __builtin_amdgcn_mfma_f32_16x16x32_bf16(afrag[q], bfrag, acc, 0, 0, 0);
    }
    const int col = nt * 16 + m;
#pragma unroll
    for (int i = 0; i < 4; ++i) {
      float v = acc[i];
      v = v >= 0.f ? v : v * LEAKY;
      out[(size_t)(r0 + quad * 4 + i) * DIM + col] = v;
    }
  }
}

// ---------------------------------------------------------------------------
// Standalone x2b (mid-ws path, where sort ran without xb fusion target)
// ---------------------------------------------------------------------------
__global__ __launch_bounds__(256) void x2b_kernel(
    const float4* __restrict__ x, ushort4* __restrict__ xb) {
  const int i = blockIdx.x * 256 + threadIdx.x;  // 3.2M exactly
  float4 v = x[i];
  ushort4 o;
  o.x = f2bf(v.x); o.y = f2bf(v.y); o.z = f2bf(v.z); o.w = f2bf(v.w);
  xb[i] = o;
}

// ---------------------------------------------------------------------------
// Fallback path (tiny ws): atomic scatter + LDS vector linear.
// ---------------------------------------------------------------------------
__global__ __launch_bounds__(256) void scatter_kernel(
    const float* __restrict__ x, const int* __restrict__ ei,
    const float* __restrict__ attr, float* __restrict__ agg) {
  int gid = blockIdx.x * blockDim.x + threadIdx.x;
  int e = gid >> 5;
  int f = (gid & 31) * 4;
  if (e >= N_EDGES) return;
  int s = ei[e];
  int d = ei[N_EDGES + e];
  float a = attr[e];
  const float4 xv = *(const float4*)(x + (size_t)s * DIM + f);
  float* dp = agg + (size_t)d * DIM + f;
  atomicAdd(dp + 0, xv.x * a);
  atomicAdd(dp + 1, xv.y * a);
  atomicAdd(dp + 2, xv.z * a);
  atomicAdd(dp + 3, xv.w * a);
}

__global__ __launch_bounds__(256, 2) void linear_kernel(
    const float* __restrict__ agg, const float* __restrict__ W,
    const float* __restrict__ bias, float* __restrict__ out) {
  __shared__ float Rs[32 * RS_STRIDE];
  __shared__ float Ws[64 * WS_STRIDE];

  const int tid = threadIdx.x;
  const int c = (tid & 31) * 4;
  const int rg = tid >> 5;
  const size_t rowBase = (size_t)blockIdx.x * 32;

  {
    const int lr = tid >> 3;
    const int col = (tid & 7) * 16;
    const float4* src = (const float4*)(agg + (rowBase + lr) * DIM + col);
#pragma unroll
    for (int j = 0; j < 4; ++j) {
      *(float4*)(Rs + lr * RS_STRIDE + col + j * 4) = src[j];
    }
  }

  const float4 bv = *(const float4*)(bias + c);
  float4 acc0 = bv, acc1 = bv, acc2 = bv, acc3 = bv;

  for (int half = 0; half < 2; ++half) {
    __syncthreads();
    {
      const int k0 = tid >> 7;
      const int o = tid & 127;
#pragma unroll
      for (int kk = k0; kk < 64; kk += 2) {
        Ws[kk * WS_STRIDE + o] = W[o * DIM + half * 64 + kk];
      }
    }
    __syncthreads();

    const float* rs0 = Rs + (rg * 4 + 0) * RS_STRIDE + half * 64;
    const float* rs1 = Rs + (rg * 4 + 1) * RS_STRIDE + half * 64;
    const float* rs2 = Rs + (rg * 4 + 2) * RS_STRIDE + half * 64;
    const float* rs3 = Rs + (rg * 4 + 3) * RS_STRIDE + half * 64;

#pragma unroll 8
    for (int k4 = 0; k4 < 16; ++k4) {
      const float4 v0 = *(const float4*)(rs0 + k4 * 4);
      const float4 v1 = *(const float4*)(rs1 + k4 * 4);
      const float4 v2 = *(const float4*)(rs2 + k4 * 4);
      const float4 v3 = *(const float4*)(rs3 + k4 * 4);
      const float4 w0 = *(const float4*)(Ws + (k4 * 4 + 0) * WS_STRIDE + c);
      const float4 w1 = *(const float4*)(Ws + (k4 * 4 + 1) * WS_STRIDE + c);
      const float4 w2 = *(const float4*)(Ws + (k4 * 4 + 2) * WS_STRIDE + c);
      const float4 w3 = *(const float4*)(Ws + (k4 * 4 + 3) * WS_STRIDE + c);

#define FMA4(acc, v)                                               \
      acc.x += v.x * w0.x + v.y * w1.x + v.z * w2.x + v.w * w3.x;  \
      acc.y += v.x * w0.y + v.y * w1.y + v.z * w2.y + v.w * w3.y;  \
      acc.z += v.x * w0.z + v.y * w1.z + v.z * w2.z + v.w * w3.z;  \
      acc.w += v.x * w0.w + v.y * w1.w + v.z * w2.w + v.w * w3.w;
      FMA4(acc0, v0)
      FMA4(acc1, v1)
      FMA4(acc2, v2)
      FMA4(acc3, v3)
#undef FMA4
    }
  }

#define LEAKY4(acc)                                   \
  acc.x = acc.x >= 0.f ? acc.x : acc.x * LEAKY;       \
  acc.y = acc.y >= 0.f ? acc.y : acc.y * LEAKY;       \
  acc.z = acc.z >= 0.f ? acc.z : acc.z * LEAKY;       \
  acc.w = acc.w >= 0.f ? acc.w : acc.w * LEAKY;
  LEAKY4(acc0) LEAKY4(acc1) LEAKY4(acc2) LEAKY4(acc3)
#undef LEAKY4

  const int row0 = (int)rowBase + rg * 4;
  *(float4*)(out + (size_t)(row0 + 0) * DIM + c) = acc0;
  *(float4*)(out + (size_t)(row0 + 1) * DIM + c) = acc1;
  *(float4*)(out + (size_t)(row0 + 2) * DIM + c) = acc2;
  *(float4*)(out + (size_t)(row0 + 3) * DIM + c) = acc3;
}

extern "C" void kernel_launch(void* const* d_in, const int* in_sizes, int n_in,
                              void* d_out, int out_size, void* d_ws, size_t ws_size,
                              hipStream_t stream) {
  const float* x = (const float*)d_in[0];
  const int* ei = (const int*)d_in[1];  // int32
  const float* attr = (const float*)d_in[2];
  const float* W = (const float*)d_in[3];
  const float* b = (const float*)d_in[4];
  float* out = (float*)d_out;

  // Workspace layout
  const size_t offBinned = 0;                             // E int2
  const size_t offCounts = 12812288;                      // 391*391 ushort
  const size_t offSrcOff = offCounts + 305920;            // 391*391 int
  const size_t offBCount = offSrcOff + 611584;            // 391 int
  const size_t offBBase  = offBCount + 1792;              // 391 int
  const size_t offCsr    = offBBase + 1792;               // E int2
  const size_t offRowPtr = offCsr + 12812288;             // N+1 int
  const size_t offWfrag  = offRowPtr + 400128;            // 32 KB
  const size_t sortNeed  = offWfrag + 32768;              // ~27.0 MB
  const size_t offXb     = sortNeed;                      // N*DIM bf16
  const size_t fullNeed  = offXb + 25600000;              // ~52.6 MB
  const size_t offAggB   = fullNeed;                      // N*DIM bf16 (packed)
  const size_t bf16Need  = offAggB + 25600000;            // ~78.2 MB

  if (ws_size >= sortNeed) {
    char* ws = (char*)d_ws;
    int2* binned = (int2*)(ws + offBinned);
    unsigned short* counts = (unsigned short*)(ws + offCounts);
    int* srcOff = (int*)(ws + offSrcOff);
    int* bucketCount = (int*)(ws + offBCount);
    int* bucketBase = (int*)(ws + offBBase);
    int2* csr = (int2*)(ws + offCsr);
    int* row_ptr = (int*)(ws + offRowPtr);
    bf16x8* wfrag = (bf16x8*)(ws + offWfrag);
    const bool haveXb = ws_size >= fullNeed;
    const bool haveAggB = ws_size >= bf16Need;
    unsigned short* xb = haveXb ? (unsigned short*)(ws + offXb) : nullptr;
    unsigned int* aggB = haveAggB ? (unsigned int*)(ws + offAggB) : nullptr;

    w_frag_kernel<<<8, 256, 0, stream>>>(W, wfrag);
    sort_local_kernel<<<NSB, 512, 0, stream>>>(ei, attr, binned, counts, srcOff,
                                               (const float4*)x, (ushort4*)xb);
    bucket_count_kernel<<<NBUCKET, 128, 0, stream>>>(counts, bucketCount);
    bucket_scan_kernel<<<1, 512, 0, stream>>>(bucketCount, bucketBase);
    passB_kernel<<<NBUCKET, 448, 0, stream>>>(binned, counts, srcOff, bucketBase,
                                              csr, row_ptr);
    if (haveAggB) {
      gather_aggb_kernel<<<N_NODES / 4, 256, 0, stream>>>(xb, row_ptr, csr, aggB);
      linear_mfma_bf16_kernel<<<(N_NODES + 63) / 64, 256, 0, stream>>>(
          (const unsigned short*)aggB, wfrag, b, out);
    } else if (haveXb) {
      gather_bf16_kernel<<<N_NODES / 4, 256, 0, stream>>>(xb, row_ptr, csr, out);
      linear_mfma_kernel<<<(N_NODES + 63) / 64, 256, 0, stream>>>(out, wfrag, b, out);
    } else {
      gather_f32_kernel<<<N_NODES / 4, 256, 0, stream>>>(x, row_ptr, csr, out);
      linear_mfma_kernel<<<(N_NODES + 63) / 64, 256, 0, stream>>>(out, wfrag, b, out);
    }
  } else {
    hipMemsetAsync(out, 0, (size_t)N_NODES * DIM * sizeof(float), stream);
    scatter_kernel<<<(N_EDGES * 32) / 256, 256, 0, stream>>>(x, ei, attr, out);
    linear_kernel<<<N_NODES / 32, 256, 0, stream>>>(out, W, b, out);
  }
}

// Round 4
// 239.395 us; speedup vs baseline: 1.0940x; 1.0421x over previous
//
#include <hip/hip_runtime.h>

#define N_NODES 100000
#define N_EDGES 1600000
#define DIM 128
#define LEAKY 0.01f
#define RS_STRIDE 132
#define WS_STRIDE 132
#define NBUCKET 391      // ceil(100000/256) nodes-per-bucket buckets (d>>8)
#define SB_EDGES 4096    // edges per sort_local block
#define NSB 391          // ceil(1600000/4096)

typedef short bf16x8 __attribute__((ext_vector_type(8)));
typedef float f32x4 __attribute__((ext_vector_type(4)));

static __device__ __forceinline__ unsigned short f2bf(float f) {
  unsigned int u = __float_as_uint(f);
  u = (u + 0x7fffu + ((u >> 16) & 1u)) >> 16;  // RNE
  return (unsigned short)u;
}

// ---------------------------------------------------------------------------
// K1: local bucket sort. Each block takes 4096 edges, histograms bucket
// (= dst>>8, 391 buckets), scans in LDS, stages sorted-by-bucket records in
// LDS, writes them out fully coalesced. Record: {src | localD<<17, attr}.
// Also emits counts[b][sb] (ushort) and srcOff[b][sb] (run start in binned).
// ---------------------------------------------------------------------------
__global__ __launch_bounds__(512) void sort_local_kernel(
    const int* __restrict__ ei, const float* __restrict__ attr,
    int2* __restrict__ binned, unsigned short* __restrict__ counts,
    int* __restrict__ srcOff) {
  __shared__ int hist[NBUCKET];
  __shared__ int cursor[NBUCKET];
  __shared__ int scanBuf[512];
  __shared__ int2 stage[SB_EDGES];  // 32 KB

  const int t = threadIdx.x;
  const int blk = blockIdx.x;
  const int base = blk * SB_EDGES;
  const int n = min(SB_EDGES, N_EDGES - base);

  if (t < NBUCKET) hist[t] = 0;
  __syncthreads();

  int myP[8];   // packed src|localD<<17, or -1 sentinel bucket
  int myB[8];
  float myA[8];
#pragma unroll
  for (int k = 0; k < 8; ++k) {
    int i = t + k * 512;
    if (i < n) {
      int e = base + i;
      int s = ei[e];
      int d = ei[N_EDGES + e];
      myA[k] = attr[e];
      myB[k] = d >> 8;
      myP[k] = s | ((d & 255) << 17);
      atomicAdd(&hist[myB[k]], 1);
    } else {
      myB[k] = -1;
    }
  }
  __syncthreads();

  // exclusive scan of hist (Hillis-Steele over 512)
  int v = (t < NBUCKET) ? hist[t] : 0;
  scanBuf[t] = v;
  __syncthreads();
  for (int off = 1; off < 512; off <<= 1) {
    int u = (t >= off) ? scanBuf[t - off] : 0;
    __syncthreads();
    scanBuf[t] += u;
    __syncthreads();
  }
  if (t < NBUCKET) {
    int excl = scanBuf[t] - v;
    cursor[t] = excl;
    counts[(size_t)t * NSB + blk] = (unsigned short)v;
    srcOff[(size_t)t * NSB + blk] = base + excl;
  }
  __syncthreads();

#pragma unroll
  for (int k = 0; k < 8; ++k) {
    if (myB[k] >= 0) {
      int loc = atomicAdd(&cursor[myB[k]], 1);
      stage[loc] = make_int2(myP[k], __float_as_int(myA[k]));
    }
  }
  __syncthreads();

  for (int i = t; i < n; i += 512) binned[base + i] = stage[i];
}

// ---------------------------------------------------------------------------
// K2a: bucketCount[b] = sum_sb counts[b][sb]
// ---------------------------------------------------------------------------
__global__ __launch_bounds__(128) void bucket_count_kernel(
    const unsigned short* __restrict__ counts, int* __restrict__ bucketCount) {
  __shared__ int red[128];
  const int b = blockIdx.x;
  const int t = threadIdx.x;
  int s = 0;
  for (int sb = t; sb < NSB; sb += 128) s += counts[(size_t)b * NSB + sb];
  red[t] = s;
  __syncthreads();
  for (int off = 64; off > 0; off >>= 1) {
    if (t < off) red[t] += red[t + off];
    __syncthreads();
  }
  if (t == 0) bucketCount[b] = red[0];
}

// ---------------------------------------------------------------------------
// K2b: exclusive scan of 391 bucket counts -> bucketBase
// ---------------------------------------------------------------------------
__global__ __launch_bounds__(512) void bucket_scan_kernel(
    const int* __restrict__ bucketCount, int* __restrict__ bucketBase) {
  __shared__ int s[512];
  const int t = threadIdx.x;
  int v = (t < NBUCKET) ? bucketCount[t] : 0;
  s[t] = v;
  __syncthreads();
  for (int off = 1; off < 512; off <<= 1) {
    int u = (t >= off) ? s[t - off] : 0;
    __syncthreads();
    s[t] += u;
    __syncthreads();
  }
  if (t < NBUCKET) bucketBase[t] = s[t] - v;
}

// ---------------------------------------------------------------------------
// K3: per-bucket counting sort -> csr + row_ptr. One block per bucket
// (256 nodes). One THREAD PER RUN (391 runs, avg len ~10.5): pass 1
// histograms, pass 2 places. All csr writes for a bucket from ONE block.
// ---------------------------------------------------------------------------
__global__ __launch_bounds__(448) void passB_kernel(
    const int2* __restrict__ binned, const unsigned short* __restrict__ counts,
    const int* __restrict__ srcOff, const int* __restrict__ bucketBase,
    int2* __restrict__ csr, int* __restrict__ row_ptr) {
  __shared__ int runSrc[NSB];
  __shared__ int runLen[NSB];
  __shared__ int hist[256];
  __shared__ int cur[256];
  __shared__ int scanBuf[256];

  const int b = blockIdx.x;
  const int t = threadIdx.x;

  if (t < NSB) {
    runSrc[t] = srcOff[(size_t)b * NSB + t];
    runLen[t] = (int)counts[(size_t)b * NSB + t];
  }
  if (t < 256) hist[t] = 0;
  __syncthreads();

  // pass 1: per-node histogram, one thread walks one run
  if (t < NSB) {
    const int src = runSrc[t];
    const int len = runLen[t];
    for (int j = 0; j < len; ++j) {
      int px = binned[src + j].x;
      atomicAdd(&hist[(px >> 17) & 255], 1);
    }
  }
  __syncthreads();

  // exclusive scan of 256 node counts
  int hv = (t < 256) ? hist[t] : 0;
  if (t < 256) scanBuf[t] = hv;
  __syncthreads();
  for (int off = 1; off < 256; off <<= 1) {
    int u = 0;
    if (t < 256 && t >= off) u = scanBuf[t - off];
    __syncthreads();
    if (t < 256) scanBuf[t] += u;
    __syncthreads();
  }
  const int bb = bucketBase[b];
  if (t < 256) {
    int excl = scanBuf[t] - hv;
    cur[t] = excl;
    int node = b * 256 + t;
    if (node < N_NODES) row_ptr[node] = bb + excl;
  }
  if (b == 0 && t == 0) row_ptr[N_NODES] = N_EDGES;
  __syncthreads();

  // pass 2: place records, one thread walks one run
  if (t < NSB) {
    const int src = runSrc[t];
    const int len = runLen[t];
    for (int j = 0; j < len; ++j) {
      int2 rec = binned[src + j];
      int ld = (rec.x >> 17) & 255;
      int pos = bb + atomicAdd(&cur[ld], 1);
      csr[pos] = make_int2(rec.x & 0x1FFFF, rec.y);
    }
  }
}

// ---------------------------------------------------------------------------
// x -> bf16 conversion (one float4 -> one ushort4 per thread)
// ---------------------------------------------------------------------------
__global__ __launch_bounds__(256) void x2b_kernel(
    const float4* __restrict__ x, ushort4* __restrict__ xb) {
  const int i = blockIdx.x * 256 + threadIdx.x;  // 3.2M exactly
  float4 v = x[i];
  ushort4 o;
  o.x = f2bf(v.x); o.y = f2bf(v.y); o.z = f2bf(v.z); o.w = f2bf(v.w);
  xb[i] = o;
}

// ---------------------------------------------------------------------------
// DUAL-STREAM gather (bf16 x) -> packed-bf16 agg. One wave per TWO nodes:
// the main loop interleaves 4 edges from each node (8 independent xb loads
// in flight = 2x the MLP of the single-stream version), then 4-unrolled +
// scalar drains for the leftover of whichever node is longer.
// ---------------------------------------------------------------------------
__global__ __launch_bounds__(256) void gather_aggb_kernel(
    const unsigned short* __restrict__ xb, const int* __restrict__ row_ptr,
    const int2* __restrict__ csr, unsigned int* __restrict__ aggB) {
  const int w = threadIdx.x >> 6;
  const int lane = threadIdx.x & 63;
  const int nA = blockIdx.x * 8 + w * 2;
  const int nB = nA + 1;

  int a = row_ptr[nA];
  const int aEnd = row_ptr[nA + 1];
  int b = row_ptr[nB];
  const int bEnd = row_ptr[nB + 1];

  float2 accA = make_float2(0.f, 0.f);
  float2 accB = make_float2(0.f, 0.f);

  // dual main loop: 4 edges per stream per iteration
  while (a + 3 < aEnd && b + 3 < bEnd) {
    int2 ea0 = csr[a];
    int2 ea1 = csr[a + 1];
    int2 ea2 = csr[a + 2];
    int2 ea3 = csr[a + 3];
    int2 eb0 = csr[b];
    int2 eb1 = csr[b + 1];
    int2 eb2 = csr[b + 2];
    int2 eb3 = csr[b + 3];
    unsigned int ua0 = *(const unsigned int*)(xb + (size_t)ea0.x * DIM + lane * 2);
    unsigned int ua1 = *(const unsigned int*)(xb + (size_t)ea1.x * DIM + lane * 2);
    unsigned int ua2 = *(const unsigned int*)(xb + (size_t)ea2.x * DIM + lane * 2);
    unsigned int ua3 = *(const unsigned int*)(xb + (size_t)ea3.x * DIM + lane * 2);
    unsigned int ub0 = *(const unsigned int*)(xb + (size_t)eb0.x * DIM + lane * 2);
    unsigned int ub1 = *(const unsigned int*)(xb + (size_t)eb1.x * DIM + lane * 2);
    unsigned int ub2 = *(const unsigned int*)(xb + (size_t)eb2.x * DIM + lane * 2);
    unsigned int ub3 = *(const unsigned int*)(xb + (size_t)eb3.x * DIM + lane * 2);
    float fa0 = __int_as_float(ea0.y), fa1 = __int_as_float(ea1.y);
    float fa2 = __int_as_float(ea2.y), fa3 = __int_as_float(ea3.y);
    float fb0 = __int_as_float(eb0.y), fb1 = __int_as_float(eb1.y);
    float fb2 = __int_as_float(eb2.y), fb3 = __int_as_float(eb3.y);
    accA.x += __uint_as_float(ua0 << 16) * fa0;
    accA.y += __uint_as_float(ua0 & 0xffff0000u) * fa0;
    accA.x += __uint_as_float(ua1 << 16) * fa1;
    accA.y += __uint_as_float(ua1 & 0xffff0000u) * fa1;
    accA.x += __uint_as_float(ua2 << 16) * fa2;
    accA.y += __uint_as_float(ua2 & 0xffff0000u) * fa2;
    accA.x += __uint_as_float(ua3 << 16) * fa3;
    accA.y += __uint_as_float(ua3 & 0xffff0000u) * fa3;
    accB.x += __uint_as_float(ub0 << 16) * fb0;
    accB.y += __uint_as_float(ub0 & 0xffff0000u) * fb0;
    accB.x += __uint_as_float(ub1 << 16) * fb1;
    accB.y += __uint_as_float(ub1 & 0xffff0000u) * fb1;
    accB.x += __uint_as_float(ub2 << 16) * fb2;
    accB.y += __uint_as_float(ub2 & 0xffff0000u) * fb2;
    accB.x += __uint_as_float(ub3 << 16) * fb3;
    accB.y += __uint_as_float(ub3 & 0xffff0000u) * fb3;
    a += 4;
    b += 4;
  }

  // drain A
  for (; a + 3 < aEnd; a += 4) {
    int2 e0 = csr[a];
    int2 e1 = csr[a + 1];
    int2 e2 = csr[a + 2];
    int2 e3 = csr[a + 3];
    unsigned int u0 = *(const unsigned int*)(xb + (size_t)e0.x * DIM + lane * 2);
    unsigned int u1 = *(const unsigned int*)(xb + (size_t)e1.x * DIM + lane * 2);
    unsigned int u2 = *(const unsigned int*)(xb + (size_t)e2.x * DIM + lane * 2);
    unsigned int u3 = *(const unsigned int*)(xb + (size_t)e3.x * DIM + lane * 2);
    float f0 = __int_as_float(e0.y), f1 = __int_as_float(e1.y);
    float f2 = __int_as_float(e2.y), f3 = __int_as_float(e3.y);
    accA.x += __uint_as_float(u0 << 16) * f0;
    accA.y += __uint_as_float(u0 & 0xffff0000u) * f0;
    accA.x += __uint_as_float(u1 << 16) * f1;
    accA.y += __uint_as_float(u1 & 0xffff0000u) * f1;
    accA.x += __uint_as_float(u2 << 16) * f2;
    accA.y += __uint_as_float(u2 & 0xffff0000u) * f2;
    accA.x += __uint_as_float(u3 << 16) * f3;
    accA.y += __uint_as_float(u3 & 0xffff0000u) * f3;
  }
  for (; a < aEnd; ++a) {
    int2 e0 = csr[a];
    float f0 = __int_as_float(e0.y);
    unsigned int u0 = *(const unsigned int*)(xb + (size_t)e0.x * DIM + lane * 2);
    accA.x += __uint_as_float(u0 << 16) * f0;
    accA.y += __uint_as_float(u0 & 0xffff0000u) * f0;
  }

  // drain B
  for (; b + 3 < bEnd; b += 4) {
    int2 e0 = csr[b];
    int2 e1 = csr[b + 1];
    int2 e2 = csr[b + 2];
    int2 e3 = csr[b + 3];
    unsigned int u0 = *(const unsigned int*)(xb + (size_t)e0.x * DIM + lane * 2);
    unsigned int u1 = *(const unsigned int*)(xb + (size_t)e1.x * DIM + lane * 2);
    unsigned int u2 = *(const unsigned int*)(xb + (size_t)e2.x * DIM + lane * 2);
    unsigned int u3 = *(const unsigned int*)(xb + (size_t)e3.x * DIM + lane * 2);
    float f0 = __int_as_float(e0.y), f1 = __int_as_float(e1.y);
    float f2 = __int_as_float(e2.y), f3 = __int_as_float(e3.y);
    accB.x += __uint_as_float(u0 << 16) * f0;
    accB.y += __uint_as_float(u0 & 0xffff0000u) * f0;
    accB.x += __uint_as_float(u1 << 16) * f1;
    accB.y += __uint_as_float(u1 & 0xffff0000u) * f1;
    accB.x += __uint_as_float(u2 << 16) * f2;
    accB.y += __uint_as_float(u2 & 0xffff0000u) * f2;
    accB.x += __uint_as_float(u3 << 16) * f3;
    accB.y += __uint_as_float(u3 & 0xffff0000u) * f3;
  }
  for (; b < bEnd; ++b) {
    int2 e0 = csr[b];
    float f0 = __int_as_float(e0.y);
    unsigned int u0 = *(const unsigned int*)(xb + (size_t)e0.x * DIM + lane * 2);
    accB.x += __uint_as_float(u0 << 16) * f0;
    accB.y += __uint_as_float(u0 & 0xffff0000u) * f0;
  }

  aggB[(size_t)nA * 64 + lane] =
      (unsigned int)f2bf(accA.x) | ((unsigned int)f2bf(accA.y) << 16);
  aggB[(size_t)nB * 64 + lane] =
      (unsigned int)f2bf(accB.x) | ((unsigned int)f2bf(accB.y) << 16);
}

// Verified r1 gather (f32 agg into out) — mid-ws fallback.
__global__ __launch_bounds__(256) void gather_bf16_kernel(
    const unsigned short* __restrict__ xb, const int* __restrict__ row_ptr,
    const int2* __restrict__ csr, float* __restrict__ out) {
  const int node = blockIdx.x * 4 + (threadIdx.x >> 6);
  const int lane = threadIdx.x & 63;

  const int beg = row_ptr[node];
  const int end = row_ptr[node + 1];

  float2 acc = make_float2(0.f, 0.f);
  int e = beg;
  for (; e + 3 < end; e += 4) {
    int2 e0 = csr[e];
    int2 e1 = csr[e + 1];
    int2 e2 = csr[e + 2];
    int2 e3 = csr[e + 3];
    unsigned int u0 = *(const unsigned int*)(xb + (size_t)e0.x * DIM + lane * 2);
    unsigned int u1 = *(const unsigned int*)(xb + (size_t)e1.x * DIM + lane * 2);
    unsigned int u2 = *(const unsigned int*)(xb + (size_t)e2.x * DIM + lane * 2);
    unsigned int u3 = *(const unsigned int*)(xb + (size_t)e3.x * DIM + lane * 2);
    float a0 = __int_as_float(e0.y), a1 = __int_as_float(e1.y);
    float a2 = __int_as_float(e2.y), a3 = __int_as_float(e3.y);
    acc.x += __uint_as_float(u0 << 16) * a0;
    acc.y += __uint_as_float(u0 & 0xffff0000u) * a0;
    acc.x += __uint_as_float(u1 << 16) * a1;
    acc.y += __uint_as_float(u1 & 0xffff0000u) * a1;
    acc.x += __uint_as_float(u2 << 16) * a2;
    acc.y += __uint_as_float(u2 & 0xffff0000u) * a2;
    acc.x += __uint_as_float(u3 << 16) * a3;
    acc.y += __uint_as_float(u3 & 0xffff0000u) * a3;
  }
  for (; e < end; ++e) {
    int2 e0 = csr[e];
    float a0 = __int_as_float(e0.y);
    unsigned int u0 = *(const unsigned int*)(xb + (size_t)e0.x * DIM + lane * 2);
    acc.x += __uint_as_float(u0 << 16) * a0;
    acc.y += __uint_as_float(u0 & 0xffff0000u) * a0;
  }
  *(float2*)(out + (size_t)node * DIM + lane * 2) = acc;
}

// fp32-x gather (used when ws can't hold xb)
__global__ __launch_bounds__(256) void gather_f32_kernel(
    const float* __restrict__ x, const int* __restrict__ row_ptr,
    const int2* __restrict__ csr, float* __restrict__ out) {
  const int node = blockIdx.x * 4 + (threadIdx.x >> 6);
  const int lane = threadIdx.x & 63;

  const int beg = row_ptr[node];
  const int end = row_ptr[node + 1];

  float2 acc = make_float2(0.f, 0.f);
  int e = beg;
  for (; e + 3 < end; e += 4) {
    int2 e0 = csr[e];
    int2 e1 = csr[e + 1];
    int2 e2 = csr[e + 2];
    int2 e3 = csr[e + 3];
    float2 v0 = *(const float2*)(x + (size_t)e0.x * DIM + lane * 2);
    float2 v1 = *(const float2*)(x + (size_t)e1.x * DIM + lane * 2);
    float2 v2 = *(const float2*)(x + (size_t)e2.x * DIM + lane * 2);
    float2 v3 = *(const float2*)(x + (size_t)e3.x * DIM + lane * 2);
    float a0 = __int_as_float(e0.y), a1 = __int_as_float(e1.y);
    float a2 = __int_as_float(e2.y), a3 = __int_as_float(e3.y);
    acc.x += v0.x * a0; acc.y += v0.y * a0;
    acc.x += v1.x * a1; acc.y += v1.y * a1;
    acc.x += v2.x * a2; acc.y += v2.y * a2;
    acc.x += v3.x * a3; acc.y += v3.y * a3;
  }
  for (; e < end; ++e) {
    int2 e0 = csr[e];
    float a0 = __int_as_float(e0.y);
    float2 v0 = *(const float2*)(x + (size_t)e0.x * DIM + lane * 2);
    acc.x += v0.x * a0; acc.y += v0.y * a0;
  }
  *(float2*)(out + (size_t)node * DIM + lane * 2) = acc;
}

// ---------------------------------------------------------------------------
// W^T -> MFMA B-fragments (bf16, lane order), 8 blocks x 256.
// ---------------------------------------------------------------------------
__global__ __launch_bounds__(256) void w_frag_kernel(
    const float* __restrict__ W, bf16x8* __restrict__ wfrag) {
  const int gid = blockIdx.x * 256 + threadIdx.x;  // 0..2047
  const int lane = gid & 63;
  const int q = (gid >> 6) & 3;
  const int nt = gid >> 8;
  const int n = nt * 16 + (lane & 15);
  const int kb = q * 32 + ((lane >> 4) & 3) * 8;
  const float4 f0 = *(const float4*)(W + n * DIM + kb);
  const float4 f1 = *(const float4*)(W + n * DIM + kb + 4);
  bf16x8 frag;
  frag[0] = (short)f2bf(f0.x); frag[1] = (short)f2bf(f0.y);
  frag[2] = (short)f2bf(f0.z); frag[3] = (short)f2bf(f0.w);
  frag[4] = (short)f2bf(f1.x); frag[5] = (short)f2bf(f1.y);
  frag[6] = (short)f2bf(f1.z); frag[7] = (short)f2bf(f1.w);
  wfrag[gid] = frag;
}

// ---------------------------------------------------------------------------
// MFMA linear from packed-bf16 agg: direct 16B fragment loads, no cvt VALU.
// out = LeakyReLU(aggB @ W^T + b).
// ---------------------------------------------------------------------------
__global__ __launch_bounds__(256) void linear_mfma_bf16_kernel(
    const unsigned short* __restrict__ aggB, const bf16x8* __restrict__ wfrag,
    const float* __restrict__ bias, float* __restrict__ out) {
  const int wave = threadIdx.x >> 6;
  const int lane = threadIdx.x & 63;
  const int r0 = (blockIdx.x * 4 + wave) * 16;
  if (r0 >= N_NODES) return;

  const int m = lane & 15;
  const int quad = lane >> 4;
  const int row = r0 + m;

  bf16x8 afrag[4];
#pragma unroll
  for (int q = 0; q < 4; ++q) {
    afrag[q] = *(const bf16x8*)(aggB + (size_t)row * DIM + q * 32 + quad * 8);
  }

#pragma unroll
  for (int nt = 0; nt < 8; ++nt) {
    const float bv = bias[nt * 16 + m];
    f32x4 acc = {bv, bv, bv, bv};
#pragma unroll
    for (int q = 0; q < 4; ++q) {
      bf16x8 bfrag = wfrag[(nt * 4 + q) * 64 + lane];
      acc = __builtin_amdgcn_mfma_f32_16x16x32_bf16(afrag[q], bfrag, acc, 0, 0, 0);
    }
    const int col = nt * 16 + m;
#pragma unroll
    for (int i = 0; i < 4; ++i) {
      float v = acc[i];
      v = v >= 0.f ? v : v * LEAKY;
      out[(size_t)(r0 + quad * 4 + i) * DIM + col] = v;
    }
  }
}

// ---------------------------------------------------------------------------
// MFMA linear from f32 agg (verified r1), in-place safe — mid-ws fallback.
// ---------------------------------------------------------------------------
__global__ __launch_bounds__(256) void linear_mfma_kernel(
    const float* __restrict__ agg, const bf16x8* __restrict__ wfrag,
    const float* __restrict__ bias, float* __restrict__ out) {
  const int wave = threadIdx.x >> 6;
  const int lane = threadIdx.x & 63;
  const int r0 = (blockIdx.x * 4 + wave) * 16;
  if (r0 >= N_NODES) return;

  const int m = lane & 15;
  const int quad = lane >> 4;
  const int row = r0 + m;

  bf16x8 afrag[4];
#pragma unroll
  for (int q = 0; q < 4; ++q) {
    const float* ap = agg + (size_t)row * DIM + q * 32 + quad * 8;
    const float4 f0 = *(const float4*)(ap);
    const float4 f1 = *(const float4*)(ap + 4);
    afrag[q][0] = (short)f2bf(f0.x); afrag[q][1] = (short)f2bf(f0.y);
    afrag[q][2] = (short)f2bf(f0.z); afrag[q][3] = (short)f2bf(f0.w);
    afrag[q][4] = (short)f2bf(f1.x); afrag[q][5] = (short)f2bf(f1.y);
    afrag[q][6] = (short)f2bf(f1.z); afrag[q][7] = (short)f2bf(f1.w);
  }

#pragma unroll
  for (int nt = 0; nt < 8; ++nt) {
    const float bv = bias[nt * 16 + m];
    f32x4 acc = {bv, bv, bv, bv};
#pragma unroll
    for (int q = 0; q < 4; ++q) {
      bf16x8 bfrag = wfrag[(nt * 4 + q) * 64 + lane];
      acc = __builtin_amdgcn_mfma_f32_16x16x32_bf16(afrag[q], bfrag, acc, 0, 0, 0);
    }
    const int col = nt * 16 + m;
#pragma unroll
    for (int i = 0; i < 4; ++i) {
      float v = acc[i];
      v = v >= 0.f ? v : v * LEAKY;
      out[(size_t)(r0 + quad * 4 + i) * DIM + col] = v;
    }
  }
}

// ---------------------------------------------------------------------------
// Fallback path (tiny ws): atomic scatter + LDS vector linear.
// ---------------------------------------------------------------------------
__global__ __launch_bounds__(256) void scatter_kernel(
    const float* __restrict__ x, const int* __restrict__ ei,
    const float* __restrict__ attr, float* __restrict__ agg) {
  int gid = blockIdx.x * blockDim.x + threadIdx.x;
  int e = gid >> 5;
  int f = (gid & 31) * 4;
  if (e >= N_EDGES) return;
  int s = ei[e];
  int d = ei[N_EDGES + e];
  float a = attr[e];
  const float4 xv = *(const float4*)(x + (size_t)s * DIM + f);
  float* dp = agg + (size_t)d * DIM + f;
  atomicAdd(dp + 0, xv.x * a);
  atomicAdd(dp + 1, xv.y * a);
  atomicAdd(dp + 2, xv.z * a);
  atomicAdd(dp + 3, xv.w * a);
}

__global__ __launch_bounds__(256, 2) void linear_kernel(
    const float* __restrict__ agg, const float* __restrict__ W,
    const float* __restrict__ bias, float* __restrict__ out) {
  __shared__ float Rs[32 * RS_STRIDE];
  __shared__ float Ws[64 * WS_STRIDE];

  const int tid = threadIdx.x;
  const int c = (tid & 31) * 4;
  const int rg = tid >> 5;
  const size_t rowBase = (size_t)blockIdx.x * 32;

  {
    const int lr = tid >> 3;
    const int col = (tid & 7) * 16;
    const float4* src = (const float4*)(agg + (rowBase + lr) * DIM + col);
#pragma unroll
    for (int j = 0; j < 4; ++j) {
      *(float4*)(Rs + lr * RS_STRIDE + col + j * 4) = src[j];
    }
  }

  const float4 bv = *(const float4*)(bias + c);
  float4 acc0 = bv, acc1 = bv, acc2 = bv, acc3 = bv;

  for (int half = 0; half < 2; ++half) {
    __syncthreads();
    {
      const int k0 = tid >> 7;
      const int o = tid & 127;
#pragma unroll
      for (int kk = k0; kk < 64; kk += 2) {
        Ws[kk * WS_STRIDE + o] = W[o * DIM + half * 64 + kk];
      }
    }
    __syncthreads();

    const float* rs0 = Rs + (rg * 4 + 0) * RS_STRIDE + half * 64;
    const float* rs1 = Rs + (rg * 4 + 1) * RS_STRIDE + half * 64;
    const float* rs2 = Rs + (rg * 4 + 2) * RS_STRIDE + half * 64;
    const float* rs3 = Rs + (rg * 4 + 3) * RS_STRIDE + half * 64;

#pragma unroll 8
    for (int k4 = 0; k4 < 16; ++k4) {
      const float4 v0 = *(const float4*)(rs0 + k4 * 4);
      const float4 v1 = *(const float4*)(rs1 + k4 * 4);
      const float4 v2 = *(const float4*)(rs2 + k4 * 4);
      const float4 v3 = *(const float4*)(rs3 + k4 * 4);
      const float4 w0 = *(const float4*)(Ws + (k4 * 4 + 0) * WS_STRIDE + c);
      const float4 w1 = *(const float4*)(Ws + (k4 * 4 + 1) * WS_STRIDE + c);
      const float4 w2 = *(const float4*)(Ws + (k4 * 4 + 2) * WS_STRIDE + c);
      const float4 w3 = *(const float4*)(Ws + (k4 * 4 + 3) * WS_STRIDE + c);

#define FMA4(acc, v)                                               \
      acc.x += v.x * w0.x + v.y * w1.x + v.z * w2.x + v.w * w3.x;  \
      acc.y += v.x * w0.y + v.y * w1.y + v.z * w2.y + v.w * w3.y;  \
      acc.z += v.x * w0.z + v.y * w1.z + v.z * w2.z + v.w * w3.z;  \
      acc.w += v.x * w0.w + v.y * w1.w + v.z * w2.w + v.w * w3.w;
      FMA4(acc0, v0)
      FMA4(acc1, v1)
      FMA4(acc2, v2)
      FMA4(acc3, v3)
#undef FMA4
    }
  }

#define LEAKY4(acc)                                   \
  acc.x = acc.x >= 0.f ? acc.x : acc.x * LEAKY;       \
  acc.y = acc.y >= 0.f ? acc.y : acc.y * LEAKY;       \
  acc.z = acc.z >= 0.f ? acc.z : acc.z * LEAKY;       \
  acc.w = acc.w >= 0.f ? acc.w : acc.w * LEAKY;
  LEAKY4(acc0) LEAKY4(acc1) LEAKY4(acc2) LEAKY4(acc3)
#undef LEAKY4

  const int row0 = (int)rowBase + rg * 4;
  *(float4*)(out + (size_t)(row0 + 0) * DIM + c) = acc0;
  *(float4*)(out + (size_t)(row0 + 1) * DIM + c) = acc1;
  *(float4*)(out + (size_t)(row0 + 2) * DIM + c) = acc2;
  *(float4*)(out + (size_t)(row0 + 3) * DIM + c) = acc3;
}

extern "C" void kernel_launch(void* const* d_in, const int* in_sizes, int n_in,
                              void* d_out, int out_size, void* d_ws, size_t ws_size,
                              hipStream_t stream) {
  const float* x = (const float*)d_in[0];
  const int* ei = (const int*)d_in[1];  // int32
  const float* attr = (const float*)d_in[2];
  const float* W = (const float*)d_in[3];
  const float* b = (const float*)d_in[4];
  float* out = (float*)d_out;

  // Workspace layout
  const size_t offBinned = 0;                             // E int2
  const size_t offCounts = 12812288;                      // 391*391 ushort
  const size_t offSrcOff = offCounts + 305920;            // 391*391 int
  const size_t offBCount = offSrcOff + 611584;            // 391 int
  const size_t offBBase  = offBCount + 1792;              // 391 int
  const size_t offCsr    = offBBase + 1792;               // E int2
  const size_t offRowPtr = offCsr + 12812288;             // N+1 int
  const size_t offWfrag  = offRowPtr + 400128;            // 32 KB
  const size_t sortNeed  = offWfrag + 32768;              // ~27.0 MB
  const size_t offXb     = sortNeed;                      // N*DIM bf16
  const size_t fullNeed  = offXb + 25600000;              // ~52.6 MB
  const size_t offAggB   = fullNeed;                      // N*DIM bf16 (packed)
  const size_t bf16Need  = offAggB + 25600000;            // ~78.2 MB

  if (ws_size >= sortNeed) {
    char* ws = (char*)d_ws;
    int2* binned = (int2*)(ws + offBinned);
    unsigned short* counts = (unsigned short*)(ws + offCounts);
    int* srcOff = (int*)(ws + offSrcOff);
    int* bucketCount = (int*)(ws + offBCount);
    int* bucketBase = (int*)(ws + offBBase);
    int2* csr = (int2*)(ws + offCsr);
    int* row_ptr = (int*)(ws + offRowPtr);
    bf16x8* wfrag = (bf16x8*)(ws + offWfrag);
    const bool haveXb = ws_size >= fullNeed;
    const bool haveAggB = ws_size >= bf16Need;
    unsigned short* xb = haveXb ? (unsigned short*)(ws + offXb) : nullptr;
    unsigned int* aggB = haveAggB ? (unsigned int*)(ws + offAggB) : nullptr;

    w_frag_kernel<<<8, 256, 0, stream>>>(W, wfrag);
    sort_local_kernel<<<NSB, 512, 0, stream>>>(ei, attr, binned, counts, srcOff);
    bucket_count_kernel<<<NBUCKET, 128, 0, stream>>>(counts, bucketCount);
    bucket_scan_kernel<<<1, 512, 0, stream>>>(bucketCount, bucketBase);
    passB_kernel<<<NBUCKET, 448, 0, stream>>>(binned, counts, srcOff, bucketBase,
                                              csr, row_ptr);
    if (haveAggB) {
      x2b_kernel<<<12500, 256, 0, stream>>>((const float4*)x, (ushort4*)xb);
      gather_aggb_kernel<<<N_NODES / 8, 256, 0, stream>>>(xb, row_ptr, csr, aggB);
      linear_mfma_bf16_kernel<<<(N_NODES + 63) / 64, 256, 0, stream>>>(
          (const unsigned short*)aggB, wfrag, b, out);
    } else if (haveXb) {
      x2b_kernel<<<12500, 256, 0, stream>>>((const float4*)x, (ushort4*)xb);
      gather_bf16_kernel<<<N_NODES / 4, 256, 0, stream>>>(xb, row_ptr, csr, out);
      linear_mfma_kernel<<<(N_NODES + 63) / 64, 256, 0, stream>>>(out, wfrag, b, out);
    } else {
      gather_f32_kernel<<<N_NODES / 4, 256, 0, stream>>>(x, row_ptr, csr, out);
      linear_mfma_kernel<<<(N_NODES + 63) / 64, 256, 0, stream>>>(out, wfrag, b, out);
    }
  } else {
    hipMemsetAsync(out, 0, (size_t)N_NODES * DIM * sizeof(float), stream);
    scatter_kernel<<<(N_EDGES * 32) / 256, 256, 0, stream>>>(x, ei, attr, out);
    linear_kernel<<<N_NODES / 32, 256, 0, stream>>>(out, W, b, out);
  }
}